// Round 2
// baseline (4457.729 us; speedup 1.0000x reference)
//
#include <hip/hip_runtime.h>

#define NN 50000
#define NE 800000
#define DD 128

// ---------------------------------------------------------------- copy
__global__ __launch_bounds__(256) void copy_f4(const float4* __restrict__ in,
                                               float4* __restrict__ out, int n) {
  int i = blockIdx.x * 256 + threadIdx.x;
  if (i < n) out[i] = in[i];
}

// ------------------------------------------------- edge message + scatter
// msg = relu(x[src] + ea*We + be); aggr[dst] += msg  (aggr pre-initialized to x)
// 8 edges/block, 32 lanes x float4 per edge.
__global__ __launch_bounds__(256) void edge_scatter(
    const float* __restrict__ x, const float* __restrict__ ea,
    const int* __restrict__ src, const int* __restrict__ dst,
    const float4* __restrict__ We4, const float4* __restrict__ be4,
    float* aggr) {
  const int t = threadIdx.x;
  const int slot = t >> 5, lane = t & 31;
  const int e = blockIdx.x * 8 + slot;
  if (e >= NE) return;
  const int s = src[e], d = dst[e];
  const float a = ea[e];
  const float4 xv = ((const float4*)(x + (size_t)s * DD))[lane];
  const float4 wv = We4[lane];
  const float4 bv = be4[lane];
  float4 m;
  m.x = fmaxf(fmaf(a, wv.x, bv.x) + xv.x, 0.f);
  m.y = fmaxf(fmaf(a, wv.y, bv.y) + xv.y, 0.f);
  m.z = fmaxf(fmaf(a, wv.z, bv.z) + xv.z, 0.f);
  m.w = fmaxf(fmaf(a, wv.w, bv.w) + xv.w, 0.f);
  float* ap = aggr + (size_t)d * DD + lane * 4;
  atomicAdd(ap + 0, m.x);
  atomicAdd(ap + 1, m.y);
  atomicAdd(ap + 2, m.z);
  atomicAdd(ap + 3, m.w);
}

// ------------------------------------------------- [nrows,128] @ [128,128]
// 32 rows/block, 128 threads, 4 rows x 8 cols per thread.
// Col split {hg*4} u {64+hg*4} keeps Wc LDS reads at free 2-way aliasing.
// Safe for in-place (out==in): each block stages its own rows before writing.
template <bool RELU, bool HASB>
__global__ __launch_bounds__(128) void gemm128(
    const float* in, const float* __restrict__ W,
    const float* __restrict__ bias, float* out, int nrows) {
  __shared__ float ins[32][132];   // +4 pad: conflict-free row reads
  __shared__ float Wc[64][128];
  const int t = threadIdx.x;
  const int row0 = blockIdx.x * 32;
  const int nr = (nrows - row0 < 32) ? (nrows - row0) : 32;

  {
    const float* base = in + (size_t)row0 * DD;
#pragma unroll
    for (int i = 0; i < 8; ++i) {
      int idx = t + i * 128;            // float4 index 0..1023
      int r = idx >> 5, k4 = (idx & 31) << 2;
      float4 v = make_float4(0.f, 0.f, 0.f, 0.f);
      if (r < nr) v = *(const float4*)(base + r * DD + k4);
      *(float4*)&ins[r][k4] = v;
    }
  }

  const int hg = t & 15, rg = t >> 4;   // rg 0..7
  const int r0 = rg * 4;
  const int cA = hg * 4, cB = 64 + hg * 4;
  float acc[4][8];
#pragma unroll
  for (int i = 0; i < 4; ++i)
#pragma unroll
    for (int j = 0; j < 8; ++j) acc[i][j] = 0.f;

  for (int kc = 0; kc < DD; kc += 64) {
    __syncthreads();
    {
      const float4* wp = (const float4*)(W + (size_t)kc * DD);
      float4* s4 = (float4*)&Wc[0][0];
#pragma unroll
      for (int i = 0; i < 16; ++i) s4[t + i * 128] = wp[t + i * 128];
    }
    __syncthreads();
    for (int kk = 0; kk < 64; kk += 4) {
      float iv[4][4];
#pragma unroll
      for (int i = 0; i < 4; ++i)
        *(float4*)&iv[i][0] = *(const float4*)&ins[r0 + i][kc + kk];
#pragma unroll
      for (int q = 0; q < 4; ++q) {
        const float4 wa = *(const float4*)&Wc[kk + q][cA];
        const float4 wb = *(const float4*)&Wc[kk + q][cB];
#pragma unroll
        for (int i = 0; i < 4; ++i) {
          const float xv = iv[i][q];
          acc[i][0] = fmaf(xv, wa.x, acc[i][0]);
          acc[i][1] = fmaf(xv, wa.y, acc[i][1]);
          acc[i][2] = fmaf(xv, wa.z, acc[i][2]);
          acc[i][3] = fmaf(xv, wa.w, acc[i][3]);
          acc[i][4] = fmaf(xv, wb.x, acc[i][4]);
          acc[i][5] = fmaf(xv, wb.y, acc[i][5]);
          acc[i][6] = fmaf(xv, wb.z, acc[i][6]);
          acc[i][7] = fmaf(xv, wb.w, acc[i][7]);
        }
      }
    }
  }

  float bA[4] = {0.f, 0.f, 0.f, 0.f}, bB[4] = {0.f, 0.f, 0.f, 0.f};
  if (HASB) {
    *(float4*)bA = *(const float4*)(bias + cA);
    *(float4*)bB = *(const float4*)(bias + cB);
  }
#pragma unroll
  for (int i = 0; i < 4; ++i) {
    const int r = r0 + i;
    if (r >= nr) continue;
    float* orow = out + (size_t)(row0 + r) * DD;
    float4 oA, oB;
    oA.x = acc[i][0] + bA[0]; oA.y = acc[i][1] + bA[1];
    oA.z = acc[i][2] + bA[2]; oA.w = acc[i][3] + bA[3];
    oB.x = acc[i][4] + bB[0]; oB.y = acc[i][5] + bB[1];
    oB.z = acc[i][6] + bB[2]; oB.w = acc[i][7] + bB[3];
    if (RELU) {
      oA.x = fmaxf(oA.x, 0.f); oA.y = fmaxf(oA.y, 0.f);
      oA.z = fmaxf(oA.z, 0.f); oA.w = fmaxf(oA.w, 0.f);
      oB.x = fmaxf(oB.x, 0.f); oB.y = fmaxf(oB.y, 0.f);
      oB.w = fmaxf(oB.w, 0.f); oB.z = fmaxf(oB.z, 0.f);
    }
    *(float4*)(orow + cA) = oA;
    *(float4*)(orow + cB) = oB;
  }
}

// ------------------------------------------------- final edge pass
// out[e] = sum_h relu(P1[src][h] + P2[dst][h]) * Wp2[h] + bp2
// (bp1 already folded into P2). 4 edges/wave, 16 lanes x 8 h each.
__global__ __launch_bounds__(256) void edge_out(
    const float* __restrict__ P1, const float* __restrict__ P2,
    const int* __restrict__ src, const int* __restrict__ dst,
    const float* __restrict__ Wp2, const float* __restrict__ bp2,
    float* __restrict__ out) {
  const int lane = threadIdx.x & 63;
  const int sub = lane >> 4;    // edge slot 0..3
  const int hg = lane & 15;     // h-chunk (8 h each)
  const int wid = (blockIdx.x * 256 + threadIdx.x) >> 6;
  const int nw = (gridDim.x * 256) >> 6;
  const float4 wA = ((const float4*)Wp2)[hg * 2];
  const float4 wB = ((const float4*)Wp2)[hg * 2 + 1];
  const float bb = bp2[0];
  for (int eb = wid * 4; eb < NE; eb += nw * 4) {
    const int e = eb + sub;
    float v = 0.f;
    if (e < NE) {
      const int s = src[e], d = dst[e];
      const float4* p1 = (const float4*)(P1 + (size_t)s * DD) + hg * 2;
      const float4* p2 = (const float4*)(P2 + (size_t)d * DD) + hg * 2;
      const float4 a0 = p1[0], a1 = p1[1];
      const float4 b0 = p2[0], b1 = p2[1];
      v  = fmaxf(a0.x + b0.x, 0.f) * wA.x + fmaxf(a0.y + b0.y, 0.f) * wA.y
         + fmaxf(a0.z + b0.z, 0.f) * wA.z + fmaxf(a0.w + b0.w, 0.f) * wA.w
         + fmaxf(a1.x + b1.x, 0.f) * wB.x + fmaxf(a1.y + b1.y, 0.f) * wB.y
         + fmaxf(a1.z + b1.z, 0.f) * wB.z + fmaxf(a1.w + b1.w, 0.f) * wB.w;
    }
    v += __shfl_down(v, 8, 64);
    v += __shfl_down(v, 4, 64);
    v += __shfl_down(v, 2, 64);
    v += __shfl_down(v, 1, 64);
    if (hg == 0 && e < NE) out[e] = v + bb;
  }
}

// ---------------------------------------------------------------- launch
extern "C" void kernel_launch(void* const* d_in, const int* in_sizes, int n_in,
                              void* d_out, int out_size, void* d_ws, size_t ws_size,
                              hipStream_t stream) {
  const float* x_in = (const float*)d_in[0];
  const float* ea   = (const float*)d_in[1];
  const int*   ei   = (const int*)d_in[2];   // harness passes integer inputs as int32
  const float* Wl1 = (const float*)d_in[3];
  const float* bl1 = (const float*)d_in[4];
  const float* Wl2 = (const float*)d_in[5];
  const float* bl2 = (const float*)d_in[6];
  const float* We  = (const float*)d_in[7];
  const float* be  = (const float*)d_in[8];
  const float* Wp1 = (const float*)d_in[9];
  const float* bp1 = (const float*)d_in[10];
  const float* Wp2 = (const float*)d_in[11];
  const float* bp2 = (const float*)d_in[12];
  const int* src = ei;
  const int* dst = ei + NE;

  float* bufA = (float*)d_ws;                       // NN*DD f32
  float* bufB = bufA + (size_t)NN * DD;             // NN*DD f32  (51.2 MB total)

  const int gemmBlocks = (NN + 31) / 32;
  const float* xl = x_in;
  float* bufs[2] = {bufA, bufB};
  for (int l = 0; l < 3; ++l) {
    float* cur = bufs[l & 1];
    copy_f4<<<(NN * DD / 4 + 255) / 256, 256, 0, stream>>>(
        (const float4*)xl, (float4*)cur, NN * DD / 4);
    edge_scatter<<<NE / 8, 256, 0, stream>>>(
        xl, ea, src, dst, (const float4*)(We + l * DD),
        (const float4*)(be + l * DD), cur);
    gemm128<true, true><<<gemmBlocks, 128, 0, stream>>>(
        cur, Wl1 + l * DD * DD, bl1 + l * DD, cur, NN);
    gemm128<true, true><<<gemmBlocks, 128, 0, stream>>>(
        cur, Wl2 + l * DD * DD, bl2 + l * DD, cur, NN);
    xl = cur;
  }
  // xl == bufA after l=2. P2 = xf @ Wp1[128:] + bp1 -> bufB; P1 in-place -> bufA.
  gemm128<false, true><<<gemmBlocks, 128, 0, stream>>>(
      bufA, Wp1 + 128 * DD, bp1, bufB, NN);
  gemm128<false, false><<<gemmBlocks, 128, 0, stream>>>(
      bufA, Wp1, (const float*)nullptr, bufA, NN);
  edge_out<<<1024, 256, 0, stream>>>(bufA, bufB, src, dst, Wp2, bp2, (float*)d_out);
}

// Round 3
// 817.284 us; speedup vs baseline: 5.4543x; 5.4543x over previous
//
#include <hip/hip_runtime.h>

#define NN 50000
#define NE 800000
#define DD 128

// ------------------------------------------------- CSR build: histogram
__global__ __launch_bounds__(256) void hist_dst(const int* __restrict__ dst,
                                                int* __restrict__ cnt) {
  int e = blockIdx.x * 256 + threadIdx.x;
  if (e < NE) atomicAdd(&cnt[dst[e]], 1);
}

// ------------------------------------------------- CSR build: scan (1 block)
__global__ __launch_bounds__(1024) void scan_nodes(const int* __restrict__ cnt,
                                                   int* __restrict__ offs,
                                                   int* __restrict__ cursor) {
  __shared__ int part[1024];
  const int t = threadIdx.x;
  const int per = (NN + 1023) / 1024;  // 49
  const int base = t * per;
  int own = 0;
  for (int i = 0; i < per; ++i) {
    int idx = base + i;
    if (idx < NN) own += cnt[idx];
  }
  part[t] = own;
  __syncthreads();
  for (int d = 1; d < 1024; d <<= 1) {
    int v = (t >= d) ? part[t - d] : 0;
    __syncthreads();
    part[t] += v;
    __syncthreads();
  }
  int run = part[t] - own;  // exclusive prefix of this thread's chunk
  for (int i = 0; i < per; ++i) {
    int idx = base + i;
    if (idx < NN) {
      offs[idx] = run;
      cursor[idx] = run;
      run += cnt[idx];
    }
  }
  if (t == 1023) offs[NN] = run;  // == NE
}

// ------------------------------------------------- CSR build: fill (reorders src/ea)
__global__ __launch_bounds__(256) void csr_fill(
    const int* __restrict__ src, const int* __restrict__ dst,
    const float* __restrict__ ea, int* __restrict__ cursor,
    int* __restrict__ srcs_s, float* __restrict__ eas_s) {
  int e = blockIdx.x * 256 + threadIdx.x;
  if (e >= NE) return;
  int pos = atomicAdd(&cursor[dst[e]], 1);
  srcs_s[pos] = src[e];
  eas_s[pos] = ea[e];
}

// ------------------------------------------------- per-node aggregation
// out[n] = x[n] + sum_{e in CSR(n)} relu(x[srcs_s[e]] + eas_s[e]*We + be)
// 32 lanes (float4 each) per node, 8 nodes per 256-thread block.
__global__ __launch_bounds__(256) void aggregate(
    const float* __restrict__ x, const int* __restrict__ offs,
    const int* __restrict__ srcs_s, const float* __restrict__ eas_s,
    const float4* __restrict__ We4, const float4* __restrict__ be4,
    float* __restrict__ out) {
  const int slot = threadIdx.x >> 5, lane = threadIdx.x & 31;
  const int n = blockIdx.x * 8 + slot;
  if (n >= NN) return;
  const float4 wv = We4[lane], bv = be4[lane];
  float4 acc = ((const float4*)(x + (size_t)n * DD))[lane];
  const int beg = offs[n], end = offs[n + 1];
  for (int i = beg; i < end; ++i) {
    const int s = srcs_s[i];
    const float a = eas_s[i];
    const float4 xv = ((const float4*)(x + (size_t)s * DD))[lane];
    acc.x += fmaxf(fmaf(a, wv.x, bv.x) + xv.x, 0.f);
    acc.y += fmaxf(fmaf(a, wv.y, bv.y) + xv.y, 0.f);
    acc.z += fmaxf(fmaf(a, wv.z, bv.z) + xv.z, 0.f);
    acc.w += fmaxf(fmaf(a, wv.w, bv.w) + xv.w, 0.f);
  }
  ((float4*)(out + (size_t)n * DD))[lane] = acc;
}

// ------------------------------------------------- [nrows,128] @ [128,128]
// 32 rows/block, 128 threads, 4 rows x 8 cols per thread.
// Safe for in-place (out==in): each block stages its own rows before writing.
template <bool RELU, bool HASB>
__global__ __launch_bounds__(128) void gemm128(
    const float* in, const float* __restrict__ W,
    const float* __restrict__ bias, float* out, int nrows) {
  __shared__ float ins[32][132];   // +4 pad: conflict-free row reads
  __shared__ float Wc[64][128];
  const int t = threadIdx.x;
  const int row0 = blockIdx.x * 32;
  const int nr = (nrows - row0 < 32) ? (nrows - row0) : 32;

  {
    const float* base = in + (size_t)row0 * DD;
#pragma unroll
    for (int i = 0; i < 8; ++i) {
      int idx = t + i * 128;            // float4 index 0..1023
      int r = idx >> 5, k4 = (idx & 31) << 2;
      float4 v = make_float4(0.f, 0.f, 0.f, 0.f);
      if (r < nr) v = *(const float4*)(base + r * DD + k4);
      *(float4*)&ins[r][k4] = v;
    }
  }

  const int hg = t & 15, rg = t >> 4;   // rg 0..7
  const int r0 = rg * 4;
  const int cA = hg * 4, cB = 64 + hg * 4;
  float acc[4][8];
#pragma unroll
  for (int i = 0; i < 4; ++i)
#pragma unroll
    for (int j = 0; j < 8; ++j) acc[i][j] = 0.f;

  for (int kc = 0; kc < DD; kc += 64) {
    __syncthreads();
    {
      const float4* wp = (const float4*)(W + (size_t)kc * DD);
      float4* s4 = (float4*)&Wc[0][0];
#pragma unroll
      for (int i = 0; i < 16; ++i) s4[t + i * 128] = wp[t + i * 128];
    }
    __syncthreads();
    for (int kk = 0; kk < 64; kk += 4) {
      float iv[4][4];
#pragma unroll
      for (int i = 0; i < 4; ++i)
        *(float4*)&iv[i][0] = *(const float4*)&ins[r0 + i][kc + kk];
#pragma unroll
      for (int q = 0; q < 4; ++q) {
        const float4 wa = *(const float4*)&Wc[kk + q][cA];
        const float4 wb = *(const float4*)&Wc[kk + q][cB];
#pragma unroll
        for (int i = 0; i < 4; ++i) {
          const float xv = iv[i][q];
          acc[i][0] = fmaf(xv, wa.x, acc[i][0]);
          acc[i][1] = fmaf(xv, wa.y, acc[i][1]);
          acc[i][2] = fmaf(xv, wa.z, acc[i][2]);
          acc[i][3] = fmaf(xv, wa.w, acc[i][3]);
          acc[i][4] = fmaf(xv, wb.x, acc[i][4]);
          acc[i][5] = fmaf(xv, wb.y, acc[i][5]);
          acc[i][6] = fmaf(xv, wb.z, acc[i][6]);
          acc[i][7] = fmaf(xv, wb.w, acc[i][7]);
        }
      }
    }
  }

  float bA[4] = {0.f, 0.f, 0.f, 0.f}, bB[4] = {0.f, 0.f, 0.f, 0.f};
  if (HASB) {
    *(float4*)bA = *(const float4*)(bias + cA);
    *(float4*)bB = *(const float4*)(bias + cB);
  }
#pragma unroll
  for (int i = 0; i < 4; ++i) {
    const int r = r0 + i;
    if (r >= nr) continue;
    float* orow = out + (size_t)(row0 + r) * DD;
    float4 oA, oB;
    oA.x = acc[i][0] + bA[0]; oA.y = acc[i][1] + bA[1];
    oA.z = acc[i][2] + bA[2]; oA.w = acc[i][3] + bA[3];
    oB.x = acc[i][4] + bB[0]; oB.y = acc[i][5] + bB[1];
    oB.z = acc[i][6] + bB[2]; oB.w = acc[i][7] + bB[3];
    if (RELU) {
      oA.x = fmaxf(oA.x, 0.f); oA.y = fmaxf(oA.y, 0.f);
      oA.z = fmaxf(oA.z, 0.f); oA.w = fmaxf(oA.w, 0.f);
      oB.x = fmaxf(oB.x, 0.f); oB.y = fmaxf(oB.y, 0.f);
      oB.z = fmaxf(oB.z, 0.f); oB.w = fmaxf(oB.w, 0.f);
    }
    *(float4*)(orow + cA) = oA;
    *(float4*)(orow + cB) = oB;
  }
}

// ------------------------------------------------- final edge pass
// out[e] = sum_h relu(P1[src][h] + P2[dst][h]) * Wp2[h] + bp2
__global__ __launch_bounds__(256) void edge_out(
    const float* __restrict__ P1, const float* __restrict__ P2,
    const int* __restrict__ src, const int* __restrict__ dst,
    const float* __restrict__ Wp2, const float* __restrict__ bp2,
    float* __restrict__ out) {
  const int lane = threadIdx.x & 63;
  const int sub = lane >> 4;    // edge slot 0..3
  const int hg = lane & 15;     // h-chunk (8 h each)
  const int wid = (blockIdx.x * 256 + threadIdx.x) >> 6;
  const int nw = (gridDim.x * 256) >> 6;
  const float4 wA = ((const float4*)Wp2)[hg * 2];
  const float4 wB = ((const float4*)Wp2)[hg * 2 + 1];
  const float bb = bp2[0];
  for (int eb = wid * 4; eb < NE; eb += nw * 4) {
    const int e = eb + sub;
    float v = 0.f;
    if (e < NE) {
      const int s = src[e], d = dst[e];
      const float4* p1 = (const float4*)(P1 + (size_t)s * DD) + hg * 2;
      const float4* p2 = (const float4*)(P2 + (size_t)d * DD) + hg * 2;
      const float4 a0 = p1[0], a1 = p1[1];
      const float4 b0 = p2[0], b1 = p2[1];
      v  = fmaxf(a0.x + b0.x, 0.f) * wA.x + fmaxf(a0.y + b0.y, 0.f) * wA.y
         + fmaxf(a0.z + b0.z, 0.f) * wA.z + fmaxf(a0.w + b0.w, 0.f) * wA.w
         + fmaxf(a1.x + b1.x, 0.f) * wB.x + fmaxf(a1.y + b1.y, 0.f) * wB.y
         + fmaxf(a1.z + b1.z, 0.f) * wB.z + fmaxf(a1.w + b1.w, 0.f) * wB.w;
    }
    v += __shfl_down(v, 8, 64);
    v += __shfl_down(v, 4, 64);
    v += __shfl_down(v, 2, 64);
    v += __shfl_down(v, 1, 64);
    if (hg == 0 && e < NE) out[e] = v + bb;
  }
}

// ---------------------------------------------------------------- launch
extern "C" void kernel_launch(void* const* d_in, const int* in_sizes, int n_in,
                              void* d_out, int out_size, void* d_ws, size_t ws_size,
                              hipStream_t stream) {
  const float* x_in = (const float*)d_in[0];
  const float* ea   = (const float*)d_in[1];
  const int*   ei   = (const int*)d_in[2];   // integer inputs arrive as int32
  const float* Wl1 = (const float*)d_in[3];
  const float* bl1 = (const float*)d_in[4];
  const float* Wl2 = (const float*)d_in[5];
  const float* bl2 = (const float*)d_in[6];
  const float* We  = (const float*)d_in[7];
  const float* be  = (const float*)d_in[8];
  const float* Wp1 = (const float*)d_in[9];
  const float* bp1 = (const float*)d_in[10];
  const float* Wp2 = (const float*)d_in[11];
  const float* bp2 = (const float*)d_in[12];
  const int* src = ei;
  const int* dst = ei + NE;

  // workspace layout
  float* bufA   = (float*)d_ws;                    // NN*DD
  float* bufB   = bufA + (size_t)NN * DD;          // NN*DD
  int*   cnt    = (int*)(bufB + (size_t)NN * DD);  // NN
  int*   offs   = cnt + NN;                        // NN+1
  int*   cursor = offs + NN + 1;                   // NN
  int*   srcs_s = cursor + NN;                     // NE
  float* eas_s  = (float*)(srcs_s + NE);           // NE   (total ~58 MB)

  // CSR build (per-launch, deterministic work)
  hipMemsetAsync(cnt, 0, NN * sizeof(int), stream);
  hist_dst<<<NE / 256, 256, 0, stream>>>(dst, cnt);
  scan_nodes<<<1, 1024, 0, stream>>>(cnt, offs, cursor);
  csr_fill<<<NE / 256, 256, 0, stream>>>(src, dst, ea, cursor, srcs_s, eas_s);

  const int gemmBlocks = (NN + 31) / 32;
  const int aggBlocks = (NN + 7) / 8;
  const float* xl = x_in;
  float* bufs[2] = {bufA, bufB};
  for (int l = 0; l < 3; ++l) {
    float* cur = bufs[l & 1];
    aggregate<<<aggBlocks, 256, 0, stream>>>(
        xl, offs, srcs_s, eas_s, (const float4*)(We + l * DD),
        (const float4*)(be + l * DD), cur);
    gemm128<true, true><<<gemmBlocks, 128, 0, stream>>>(
        cur, Wl1 + l * DD * DD, bl1 + l * DD, cur, NN);
    gemm128<true, true><<<gemmBlocks, 128, 0, stream>>>(
        cur, Wl2 + l * DD * DD, bl2 + l * DD, cur, NN);
    xl = cur;
  }
  // xl == bufA. P2 = xf @ Wp1[128:] + bp1 -> bufB; P1 = xf @ Wp1[:128] in-place.
  gemm128<false, true><<<gemmBlocks, 128, 0, stream>>>(
      bufA, Wp1 + 128 * DD, bp1, bufB, NN);
  gemm128<false, false><<<gemmBlocks, 128, 0, stream>>>(
      bufA, Wp1, (const float*)nullptr, bufA, NN);
  edge_out<<<1024, 256, 0, stream>>>(bufA, bufB, src, dst, Wp2, bp2, (float*)d_out);
}

// Round 4
// 697.761 us; speedup vs baseline: 6.3886x; 1.1713x over previous
//
#include <hip/hip_runtime.h>

#define NN 50000
#define NE 800000
#define DD 128

// ------------------------------------------------- CSR build: histogram
__global__ __launch_bounds__(256) void hist_dst(const int* __restrict__ dst,
                                                int* __restrict__ cnt) {
  int e = blockIdx.x * 256 + threadIdx.x;
  if (e < NE) atomicAdd(&cnt[dst[e]], 1);
}

// ------------------------------------------------- CSR build: scan (1 block)
// Tiled: 1024 threads x 8 contiguous ints (int4 x2, coalesced), shfl-scan
// within wave, 16 wave-sums scanned by wave 0, serial carry across 7 tiles.
__global__ __launch_bounds__(1024) void scan_nodes(const int* __restrict__ cnt,
                                                   int* __restrict__ offs,
                                                   int* __restrict__ cursor) {
  __shared__ int wsum[16];
  __shared__ int wpre[16];
  const int t = threadIdx.x;
  const int lane = t & 63, wv = t >> 6;
  int carry = 0;
  for (int base = 0; base < NN; base += 8192) {
    const int i0 = base + t * 8;
    int4 a = make_int4(0, 0, 0, 0), b = make_int4(0, 0, 0, 0);
    if (i0 + 8 <= NN) {
      a = *(const int4*)(cnt + i0);
      b = *(const int4*)(cnt + i0 + 4);
    } else if (i0 < NN) {
      int tmp[8];
      for (int j = 0; j < 8; ++j) tmp[j] = (i0 + j < NN) ? cnt[i0 + j] : 0;
      a = make_int4(tmp[0], tmp[1], tmp[2], tmp[3]);
      b = make_int4(tmp[4], tmp[5], tmp[6], tmp[7]);
    }
    const int own = a.x + a.y + a.z + a.w + b.x + b.y + b.z + b.w;
    int inc = own;                      // inclusive scan within wave
#pragma unroll
    for (int d = 1; d < 64; d <<= 1) {
      int v = __shfl_up(inc, d, 64);
      if (lane >= d) inc += v;
    }
    if (lane == 63) wsum[wv] = inc;
    __syncthreads();
    if (t < 16) {
      int v = wsum[t];
      int p = v;
#pragma unroll
      for (int d = 1; d < 16; d <<= 1) {
        int u = __shfl_up(p, d, 16);
        if (t >= d) p += u;
      }
      wpre[t] = p - v;                  // exclusive wave prefix
      if (t == 15) wsum[15] = p;        // tile total
    }
    __syncthreads();
    int run = carry + wpre[wv] + inc - own;
    const int o0 = run,      o1 = o0 + a.x, o2 = o1 + a.y, o3 = o2 + a.z;
    const int o4 = o3 + a.w, o5 = o4 + b.x, o6 = o5 + b.y, o7 = o6 + b.z;
    if (i0 + 8 <= NN) {
      *(int4*)(offs + i0)       = make_int4(o0, o1, o2, o3);
      *(int4*)(offs + i0 + 4)   = make_int4(o4, o5, o6, o7);
      *(int4*)(cursor + i0)     = make_int4(o0, o1, o2, o3);
      *(int4*)(cursor + i0 + 4) = make_int4(o4, o5, o6, o7);
    } else if (i0 < NN) {
      const int o[8] = {o0, o1, o2, o3, o4, o5, o6, o7};
      for (int j = 0; j < 8; ++j)
        if (i0 + j < NN) { offs[i0 + j] = o[j]; cursor[i0 + j] = o[j]; }
    }
    carry += wsum[15];
    __syncthreads();                    // protect wsum/wpre before next tile
  }
  if (t == 0) offs[NN] = carry;
}

// ------------------------------------------------- CSR build: fill (reorders src/ea)
__global__ __launch_bounds__(256) void csr_fill(
    const int* __restrict__ src, const int* __restrict__ dst,
    const float* __restrict__ ea, int* __restrict__ cursor,
    int* __restrict__ srcs_s, float* __restrict__ eas_s) {
  int e = blockIdx.x * 256 + threadIdx.x;
  if (e >= NE) return;
  int pos = atomicAdd(&cursor[dst[e]], 1);
  srcs_s[pos] = src[e];
  eas_s[pos] = ea[e];
}

// ------------------------------------------------- per-node aggregation
// out[n] = x[n] + sum_{e in CSR(n)} relu(x[srcs_s[e]] + eas_s[e]*We + be)
// 32 lanes (float4 each) per node, 8 nodes per 256-thread block.
__global__ __launch_bounds__(256) void aggregate(
    const float* __restrict__ x, const int* __restrict__ offs,
    const int* __restrict__ srcs_s, const float* __restrict__ eas_s,
    const float4* __restrict__ We4, const float4* __restrict__ be4,
    float* __restrict__ out) {
  const int slot = threadIdx.x >> 5, lane = threadIdx.x & 31;
  const int n = blockIdx.x * 8 + slot;
  if (n >= NN) return;
  const float4 wv = We4[lane], bv = be4[lane];
  float4 acc = ((const float4*)(x + (size_t)n * DD))[lane];
  const int beg = offs[n], end = offs[n + 1];
  for (int i = beg; i < end; ++i) {
    const int s = srcs_s[i];
    const float a = eas_s[i];
    const float4 xv = ((const float4*)(x + (size_t)s * DD))[lane];
    acc.x += fmaxf(fmaf(a, wv.x, bv.x) + xv.x, 0.f);
    acc.y += fmaxf(fmaf(a, wv.y, bv.y) + xv.y, 0.f);
    acc.z += fmaxf(fmaf(a, wv.z, bv.z) + xv.z, 0.f);
    acc.w += fmaxf(fmaf(a, wv.w, bv.w) + xv.w, 0.f);
  }
  ((float4*)(out + (size_t)n * DD))[lane] = acc;
}

// ------------------------------------------------- [nrows,128] @ [128,128]
// 32 rows/block, 128 threads, 4 rows x 8 cols per thread.
// Safe for in-place (out==in): each block stages its own rows before writing.
template <bool RELU, bool HASB>
__global__ __launch_bounds__(128) void gemm128(
    const float* in, const float* __restrict__ W,
    const float* __restrict__ bias, float* out, int nrows) {
  __shared__ float ins[32][132];   // +4 pad: conflict-free row reads
  __shared__ float Wc[64][128];
  const int t = threadIdx.x;
  const int row0 = blockIdx.x * 32;
  const int nr = (nrows - row0 < 32) ? (nrows - row0) : 32;

  {
    const float* base = in + (size_t)row0 * DD;
#pragma unroll
    for (int i = 0; i < 8; ++i) {
      int idx = t + i * 128;            // float4 index 0..1023
      int r = idx >> 5, k4 = (idx & 31) << 2;
      float4 v = make_float4(0.f, 0.f, 0.f, 0.f);
      if (r < nr) v = *(const float4*)(base + r * DD + k4);
      *(float4*)&ins[r][k4] = v;
    }
  }

  const int hg = t & 15, rg = t >> 4;   // rg 0..7
  const int r0 = rg * 4;
  const int cA = hg * 4, cB = 64 + hg * 4;
  float acc[4][8];
#pragma unroll
  for (int i = 0; i < 4; ++i)
#pragma unroll
    for (int j = 0; j < 8; ++j) acc[i][j] = 0.f;

  for (int kc = 0; kc < DD; kc += 64) {
    __syncthreads();
    {
      const float4* wp = (const float4*)(W + (size_t)kc * DD);
      float4* s4 = (float4*)&Wc[0][0];
#pragma unroll
      for (int i = 0; i < 16; ++i) s4[t + i * 128] = wp[t + i * 128];
    }
    __syncthreads();
    for (int kk = 0; kk < 64; kk += 4) {
      float iv[4][4];
#pragma unroll
      for (int i = 0; i < 4; ++i)
        *(float4*)&iv[i][0] = *(const float4*)&ins[r0 + i][kc + kk];
#pragma unroll
      for (int q = 0; q < 4; ++q) {
        const float4 wa = *(const float4*)&Wc[kk + q][cA];
        const float4 wb = *(const float4*)&Wc[kk + q][cB];
#pragma unroll
        for (int i = 0; i < 4; ++i) {
          const float xv = iv[i][q];
          acc[i][0] = fmaf(xv, wa.x, acc[i][0]);
          acc[i][1] = fmaf(xv, wa.y, acc[i][1]);
          acc[i][2] = fmaf(xv, wa.z, acc[i][2]);
          acc[i][3] = fmaf(xv, wa.w, acc[i][3]);
          acc[i][4] = fmaf(xv, wb.x, acc[i][4]);
          acc[i][5] = fmaf(xv, wb.y, acc[i][5]);
          acc[i][6] = fmaf(xv, wb.z, acc[i][6]);
          acc[i][7] = fmaf(xv, wb.w, acc[i][7]);
        }
      }
    }
  }

  float bA[4] = {0.f, 0.f, 0.f, 0.f}, bB[4] = {0.f, 0.f, 0.f, 0.f};
  if (HASB) {
    *(float4*)bA = *(const float4*)(bias + cA);
    *(float4*)bB = *(const float4*)(bias + cB);
  }
#pragma unroll
  for (int i = 0; i < 4; ++i) {
    const int r = r0 + i;
    if (r >= nr) continue;
    float* orow = out + (size_t)(row0 + r) * DD;
    float4 oA, oB;
    oA.x = acc[i][0] + bA[0]; oA.y = acc[i][1] + bA[1];
    oA.z = acc[i][2] + bA[2]; oA.w = acc[i][3] + bA[3];
    oB.x = acc[i][4] + bB[0]; oB.y = acc[i][5] + bB[1];
    oB.z = acc[i][6] + bB[2]; oB.w = acc[i][7] + bB[3];
    if (RELU) {
      oA.x = fmaxf(oA.x, 0.f); oA.y = fmaxf(oA.y, 0.f);
      oA.z = fmaxf(oA.z, 0.f); oA.w = fmaxf(oA.w, 0.f);
      oB.x = fmaxf(oB.x, 0.f); oB.y = fmaxf(oB.y, 0.f);
      oB.z = fmaxf(oB.z, 0.f); oB.w = fmaxf(oB.w, 0.f);
    }
    *(float4*)(orow + cA) = oA;
    *(float4*)(orow + cB) = oB;
  }
}

// ------------------------------------------------- final edge pass
// out[e] = sum_h relu(P1[src][h] + P2[dst][h]) * Wp2[h] + bp2
__global__ __launch_bounds__(256) void edge_out(
    const float* __restrict__ P1, const float* __restrict__ P2,
    const int* __restrict__ src, const int* __restrict__ dst,
    const float* __restrict__ Wp2, const float* __restrict__ bp2,
    float* __restrict__ out) {
  const int lane = threadIdx.x & 63;
  const int sub = lane >> 4;    // edge slot 0..3
  const int hg = lane & 15;     // h-chunk (8 h each)
  const int wid = (blockIdx.x * 256 + threadIdx.x) >> 6;
  const int nw = (gridDim.x * 256) >> 6;
  const float4 wA = ((const float4*)Wp2)[hg * 2];
  const float4 wB = ((const float4*)Wp2)[hg * 2 + 1];
  const float bb = bp2[0];
  for (int eb = wid * 4; eb < NE; eb += nw * 4) {
    const int e = eb + sub;
    float v = 0.f;
    if (e < NE) {
      const int s = src[e], d = dst[e];
      const float4* p1 = (const float4*)(P1 + (size_t)s * DD) + hg * 2;
      const float4* p2 = (const float4*)(P2 + (size_t)d * DD) + hg * 2;
      const float4 a0 = p1[0], a1 = p1[1];
      const float4 b0 = p2[0], b1 = p2[1];
      v  = fmaxf(a0.x + b0.x, 0.f) * wA.x + fmaxf(a0.y + b0.y, 0.f) * wA.y
         + fmaxf(a0.z + b0.z, 0.f) * wA.z + fmaxf(a0.w + b0.w, 0.f) * wA.w
         + fmaxf(a1.x + b1.x, 0.f) * wB.x + fmaxf(a1.y + b1.y, 0.f) * wB.y
         + fmaxf(a1.z + b1.z, 0.f) * wB.z + fmaxf(a1.w + b1.w, 0.f) * wB.w;
    }
    v += __shfl_down(v, 8, 64);
    v += __shfl_down(v, 4, 64);
    v += __shfl_down(v, 2, 64);
    v += __shfl_down(v, 1, 64);
    if (hg == 0 && e < NE) out[e] = v + bb;
  }
}

// ---------------------------------------------------------------- launch
extern "C" void kernel_launch(void* const* d_in, const int* in_sizes, int n_in,
                              void* d_out, int out_size, void* d_ws, size_t ws_size,
                              hipStream_t stream) {
  const float* x_in = (const float*)d_in[0];
  const float* ea   = (const float*)d_in[1];
  const int*   ei   = (const int*)d_in[2];   // integer inputs arrive as int32
  const float* Wl1 = (const float*)d_in[3];
  const float* bl1 = (const float*)d_in[4];
  const float* Wl2 = (const float*)d_in[5];
  const float* bl2 = (const float*)d_in[6];
  const float* We  = (const float*)d_in[7];
  const float* be  = (const float*)d_in[8];
  const float* Wp1 = (const float*)d_in[9];
  const float* bp1 = (const float*)d_in[10];
  const float* Wp2 = (const float*)d_in[11];
  const float* bp2 = (const float*)d_in[12];
  const int* src = ei;
  const int* dst = ei + NE;

  // workspace layout
  float* bufA   = (float*)d_ws;                    // NN*DD
  float* bufB   = bufA + (size_t)NN * DD;          // NN*DD
  int*   cnt    = (int*)(bufB + (size_t)NN * DD);  // NN
  int*   offs   = cnt + NN;                        // NN+1
  int*   cursor = offs + NN + 1;                   // NN
  int*   srcs_s = cursor + NN;                     // NE
  float* eas_s  = (float*)(srcs_s + NE);           // NE   (total ~58 MB)

  // CSR build (per-launch, deterministic work)
  hipMemsetAsync(cnt, 0, NN * sizeof(int), stream);
  hist_dst<<<NE / 256, 256, 0, stream>>>(dst, cnt);
  scan_nodes<<<1, 1024, 0, stream>>>(cnt, offs, cursor);
  csr_fill<<<NE / 256, 256, 0, stream>>>(src, dst, ea, cursor, srcs_s, eas_s);

  const int gemmBlocks = (NN + 31) / 32;
  const int aggBlocks = (NN + 7) / 8;
  const float* xl = x_in;
  float* bufs[2] = {bufA, bufB};
  for (int l = 0; l < 3; ++l) {
    float* cur = bufs[l & 1];
    aggregate<<<aggBlocks, 256, 0, stream>>>(
        xl, offs, srcs_s, eas_s, (const float4*)(We + l * DD),
        (const float4*)(be + l * DD), cur);
    gemm128<true, true><<<gemmBlocks, 128, 0, stream>>>(
        cur, Wl1 + l * DD * DD, bl1 + l * DD, cur, NN);
    gemm128<true, true><<<gemmBlocks, 128, 0, stream>>>(
        cur, Wl2 + l * DD * DD, bl2 + l * DD, cur, NN);
    xl = cur;
  }
  // xl == bufA. P2 = xf @ Wp1[128:] + bp1 -> bufB; P1 = xf @ Wp1[:128] in-place.
  gemm128<false, true><<<gemmBlocks, 128, 0, stream>>>(
      bufA, Wp1 + 128 * DD, bp1, bufB, NN);
  gemm128<false, false><<<gemmBlocks, 128, 0, stream>>>(
      bufA, Wp1, (const float*)nullptr, bufA, NN);
  edge_out<<<1024, 256, 0, stream>>>(bufA, bufB, src, dst, Wp2, bp2, (float*)d_out);
}

// Round 5
// 619.216 us; speedup vs baseline: 7.1990x; 1.1268x over previous
//
#include <hip/hip_runtime.h>

#define NN 50000
#define NE 800000
#define DD 128

// ------------------------------------------------- CSR build: histogram
__global__ __launch_bounds__(256) void hist_dst(const int* __restrict__ dst,
                                                int* __restrict__ cnt) {
  int e = blockIdx.x * 256 + threadIdx.x;
  if (e < NE) atomicAdd(&cnt[dst[e]], 1);
}

// ------------------------------------------------- CSR build: scan (1 block)
__global__ __launch_bounds__(1024) void scan_nodes(const int* __restrict__ cnt,
                                                   int* __restrict__ offs,
                                                   int* __restrict__ cursor) {
  __shared__ int wsum[16];
  __shared__ int wpre[16];
  const int t = threadIdx.x;
  const int lane = t & 63, wv = t >> 6;
  int carry = 0;
  for (int base = 0; base < NN; base += 8192) {
    const int i0 = base + t * 8;
    int4 a = make_int4(0, 0, 0, 0), b = make_int4(0, 0, 0, 0);
    if (i0 + 8 <= NN) {
      a = *(const int4*)(cnt + i0);
      b = *(const int4*)(cnt + i0 + 4);
    } else if (i0 < NN) {
      int tmp[8];
      for (int j = 0; j < 8; ++j) tmp[j] = (i0 + j < NN) ? cnt[i0 + j] : 0;
      a = make_int4(tmp[0], tmp[1], tmp[2], tmp[3]);
      b = make_int4(tmp[4], tmp[5], tmp[6], tmp[7]);
    }
    const int own = a.x + a.y + a.z + a.w + b.x + b.y + b.z + b.w;
    int inc = own;
#pragma unroll
    for (int d = 1; d < 64; d <<= 1) {
      int v = __shfl_up(inc, d, 64);
      if (lane >= d) inc += v;
    }
    if (lane == 63) wsum[wv] = inc;
    __syncthreads();
    if (t < 16) {
      int v = wsum[t];
      int p = v;
#pragma unroll
      for (int d = 1; d < 16; d <<= 1) {
        int u = __shfl_up(p, d, 16);
        if (t >= d) p += u;
      }
      wpre[t] = p - v;
      if (t == 15) wsum[15] = p;
    }
    __syncthreads();
    int run = carry + wpre[wv] + inc - own;
    const int o0 = run,      o1 = o0 + a.x, o2 = o1 + a.y, o3 = o2 + a.z;
    const int o4 = o3 + a.w, o5 = o4 + b.x, o6 = o5 + b.y, o7 = o6 + b.z;
    if (i0 + 8 <= NN) {
      *(int4*)(offs + i0)       = make_int4(o0, o1, o2, o3);
      *(int4*)(offs + i0 + 4)   = make_int4(o4, o5, o6, o7);
      *(int4*)(cursor + i0)     = make_int4(o0, o1, o2, o3);
      *(int4*)(cursor + i0 + 4) = make_int4(o4, o5, o6, o7);
    } else if (i0 < NN) {
      const int o[8] = {o0, o1, o2, o3, o4, o5, o6, o7};
      for (int j = 0; j < 8; ++j)
        if (i0 + j < NN) { offs[i0 + j] = o[j]; cursor[i0 + j] = o[j]; }
    }
    carry += wsum[15];
    __syncthreads();
  }
  if (t == 0) offs[NN] = carry;
}

// ------------------------------------------------- CSR build: fill
__global__ __launch_bounds__(256) void csr_fill(
    const int* __restrict__ src, const int* __restrict__ dst,
    const float* __restrict__ ea, int* __restrict__ cursor,
    int* __restrict__ srcs_s, float* __restrict__ eas_s,
    int* __restrict__ eid_s) {
  int e = blockIdx.x * 256 + threadIdx.x;
  if (e >= NE) return;
  int pos = atomicAdd(&cursor[dst[e]], 1);
  srcs_s[pos] = src[e];
  eas_s[pos] = ea[e];
  eid_s[pos] = e;
}

// ------------------------------------------------- per-node aggregation
// out[n] = x[n] + sum_{e in CSR(n)} relu(x[src_e] + ea_e*We + be)
// 32 lanes (float4) per node, 2x unrolled for memory-level parallelism.
__global__ __launch_bounds__(256) void aggregate(
    const float* __restrict__ x, const int* __restrict__ offs,
    const int* __restrict__ srcs_s, const float* __restrict__ eas_s,
    const float4* __restrict__ We4, const float4* __restrict__ be4,
    float* __restrict__ out) {
  const int slot = threadIdx.x >> 5, lane = threadIdx.x & 31;
  const int n = blockIdx.x * 8 + slot;
  if (n >= NN) return;
  const float4 wv = We4[lane], bv = be4[lane];
  float4 acc0 = ((const float4*)(x + (size_t)n * DD))[lane];
  float4 acc1 = make_float4(0.f, 0.f, 0.f, 0.f);
  const int beg = offs[n], end = offs[n + 1];
  int i = beg;
  for (; i + 2 <= end; i += 2) {
    const int s0 = srcs_s[i], s1 = srcs_s[i + 1];
    const float a0 = eas_s[i], a1 = eas_s[i + 1];
    const float4 x0 = ((const float4*)(x + (size_t)s0 * DD))[lane];
    const float4 x1 = ((const float4*)(x + (size_t)s1 * DD))[lane];
    acc0.x += fmaxf(fmaf(a0, wv.x, bv.x) + x0.x, 0.f);
    acc0.y += fmaxf(fmaf(a0, wv.y, bv.y) + x0.y, 0.f);
    acc0.z += fmaxf(fmaf(a0, wv.z, bv.z) + x0.z, 0.f);
    acc0.w += fmaxf(fmaf(a0, wv.w, bv.w) + x0.w, 0.f);
    acc1.x += fmaxf(fmaf(a1, wv.x, bv.x) + x1.x, 0.f);
    acc1.y += fmaxf(fmaf(a1, wv.y, bv.y) + x1.y, 0.f);
    acc1.z += fmaxf(fmaf(a1, wv.z, bv.z) + x1.z, 0.f);
    acc1.w += fmaxf(fmaf(a1, wv.w, bv.w) + x1.w, 0.f);
  }
  if (i < end) {
    const int s0 = srcs_s[i];
    const float a0 = eas_s[i];
    const float4 x0 = ((const float4*)(x + (size_t)s0 * DD))[lane];
    acc0.x += fmaxf(fmaf(a0, wv.x, bv.x) + x0.x, 0.f);
    acc0.y += fmaxf(fmaf(a0, wv.y, bv.y) + x0.y, 0.f);
    acc0.z += fmaxf(fmaf(a0, wv.z, bv.z) + x0.z, 0.f);
    acc0.w += fmaxf(fmaf(a0, wv.w, bv.w) + x0.w, 0.f);
  }
  acc0.x += acc1.x; acc0.y += acc1.y; acc0.z += acc1.z; acc0.w += acc1.w;
  ((float4*)(out + (size_t)n * DD))[lane] = acc0;
}

// ------------------------------------------------- fused layer MLP
// out = relu(relu(in@W1 + b1)@W2 + b2).  64 rows / 256 threads / 4x8 tile.
// h is written back into the ins LDS buffer.  In-place-safe (out==in).
__global__ __launch_bounds__(256) void fused_mlp(
    const float* in, const float* __restrict__ W1, const float* __restrict__ b1,
    const float* __restrict__ W2, const float* __restrict__ b2,
    float* out, int nrows) {
  __shared__ float ins[64][132];
  __shared__ float Wc[32][128];
  const int t = threadIdx.x;
  const int row0 = blockIdx.x * 64;
  const int nr = (nrows - row0 < 64) ? (nrows - row0) : 64;

  {
    const float* base = in + (size_t)row0 * DD;
#pragma unroll
    for (int i = 0; i < 8; ++i) {
      int idx = t + i * 256;            // float4 index 0..2047
      int r = idx >> 5, k4 = (idx & 31) << 2;
      float4 v = make_float4(0.f, 0.f, 0.f, 0.f);
      if (r < nr) v = *(const float4*)(base + r * DD + k4);
      *(float4*)&ins[r][k4] = v;
    }
  }

  const int hg = t & 15, rg = t >> 4;   // rg 0..15
  const int r0 = rg * 4;
  const int cA = hg * 4, cB = 64 + hg * 4;
  float acc[4][8];
#pragma unroll
  for (int i = 0; i < 4; ++i)
#pragma unroll
    for (int j = 0; j < 8; ++j) acc[i][j] = 0.f;

#define GEMM_CHUNKS(WPTR)                                                  \
  for (int kc = 0; kc < DD; kc += 32) {                                    \
    __syncthreads();                                                       \
    {                                                                      \
      const float4* wp = (const float4*)((WPTR) + (size_t)kc * DD);        \
      float4* s4 = (float4*)&Wc[0][0];                                     \
      _Pragma("unroll")                                                    \
      for (int i = 0; i < 4; ++i) s4[t + i * 256] = wp[t + i * 256];       \
    }                                                                      \
    __syncthreads();                                                       \
    for (int kk = 0; kk < 32; kk += 4) {                                   \
      float iv[4][4];                                                      \
      _Pragma("unroll")                                                    \
      for (int i = 0; i < 4; ++i)                                          \
        *(float4*)&iv[i][0] = *(const float4*)&ins[r0 + i][kc + kk];       \
      _Pragma("unroll")                                                    \
      for (int q = 0; q < 4; ++q) {                                        \
        const float4 wa = *(const float4*)&Wc[kk + q][cA];                 \
        const float4 wb = *(const float4*)&Wc[kk + q][cB];                 \
        _Pragma("unroll")                                                  \
        for (int i = 0; i < 4; ++i) {                                      \
          const float xv = iv[i][q];                                       \
          acc[i][0] = fmaf(xv, wa.x, acc[i][0]);                           \
          acc[i][1] = fmaf(xv, wa.y, acc[i][1]);                           \
          acc[i][2] = fmaf(xv, wa.z, acc[i][2]);                           \
          acc[i][3] = fmaf(xv, wa.w, acc[i][3]);                           \
          acc[i][4] = fmaf(xv, wb.x, acc[i][4]);                           \
          acc[i][5] = fmaf(xv, wb.y, acc[i][5]);                           \
          acc[i][6] = fmaf(xv, wb.z, acc[i][6]);                           \
          acc[i][7] = fmaf(xv, wb.w, acc[i][7]);                           \
        }                                                                  \
      }                                                                    \
    }                                                                      \
  }

  GEMM_CHUNKS(W1)

  // h = relu(acc + b1) -> back into ins
  {
    const float4 bA = *(const float4*)(b1 + cA);
    const float4 bB = *(const float4*)(b1 + cB);
    __syncthreads();                    // all gemm1 reads of ins done
#pragma unroll
    for (int i = 0; i < 4; ++i) {
      float4 hA, hB;
      hA.x = fmaxf(acc[i][0] + bA.x, 0.f); hA.y = fmaxf(acc[i][1] + bA.y, 0.f);
      hA.z = fmaxf(acc[i][2] + bA.z, 0.f); hA.w = fmaxf(acc[i][3] + bA.w, 0.f);
      hB.x = fmaxf(acc[i][4] + bB.x, 0.f); hB.y = fmaxf(acc[i][5] + bB.y, 0.f);
      hB.z = fmaxf(acc[i][6] + bB.z, 0.f); hB.w = fmaxf(acc[i][7] + bB.w, 0.f);
      *(float4*)&ins[r0 + i][cA] = hA;
      *(float4*)&ins[r0 + i][cB] = hB;
      acc[i][0] = acc[i][1] = acc[i][2] = acc[i][3] = 0.f;
      acc[i][4] = acc[i][5] = acc[i][6] = acc[i][7] = 0.f;
    }
  }

  GEMM_CHUNKS(W2)

  const float4 bA = *(const float4*)(b2 + cA);
  const float4 bB = *(const float4*)(b2 + cB);
#pragma unroll
  for (int i = 0; i < 4; ++i) {
    const int r = r0 + i;
    if (r >= nr) continue;
    float* orow = out + (size_t)(row0 + r) * DD;
    float4 oA, oB;
    oA.x = fmaxf(acc[i][0] + bA.x, 0.f); oA.y = fmaxf(acc[i][1] + bA.y, 0.f);
    oA.z = fmaxf(acc[i][2] + bA.z, 0.f); oA.w = fmaxf(acc[i][3] + bA.w, 0.f);
    oB.x = fmaxf(acc[i][4] + bB.x, 0.f); oB.y = fmaxf(acc[i][5] + bB.y, 0.f);
    oB.z = fmaxf(acc[i][6] + bB.z, 0.f); oB.w = fmaxf(acc[i][7] + bB.w, 0.f);
    *(float4*)(orow + cA) = oA;
    *(float4*)(orow + cB) = oB;
  }
}

// ------------------------------------------------- predictor: P1,P2 from xf
// P1 = xf @ Wp1[:128] (no bias); P2 = xf @ Wp1[128:] + bp1.
// One staging of xf; P1 may alias in (own-rows-only writes after staging).
__global__ __launch_bounds__(256) void gemm_pred(
    const float* in, const float* __restrict__ Wp1, const float* __restrict__ bp1,
    float* P1, float* P2, int nrows) {
  __shared__ float ins[64][132];
  __shared__ float Wc[32][128];
  const int t = threadIdx.x;
  const int row0 = blockIdx.x * 64;
  const int nr = (nrows - row0 < 64) ? (nrows - row0) : 64;

  {
    const float* base = in + (size_t)row0 * DD;
#pragma unroll
    for (int i = 0; i < 8; ++i) {
      int idx = t + i * 256;
      int r = idx >> 5, k4 = (idx & 31) << 2;
      float4 v = make_float4(0.f, 0.f, 0.f, 0.f);
      if (r < nr) v = *(const float4*)(base + r * DD + k4);
      *(float4*)&ins[r][k4] = v;
    }
  }

  const int hg = t & 15, rg = t >> 4;
  const int r0 = rg * 4;
  const int cA = hg * 4, cB = 64 + hg * 4;
  float acc[4][8];
#pragma unroll
  for (int i = 0; i < 4; ++i)
#pragma unroll
    for (int j = 0; j < 8; ++j) acc[i][j] = 0.f;

  GEMM_CHUNKS(Wp1)

#pragma unroll
  for (int i = 0; i < 4; ++i) {
    const int r = r0 + i;
    if (r < nr) {
      float* orow = P1 + (size_t)(row0 + r) * DD;
      *(float4*)(orow + cA) = make_float4(acc[i][0], acc[i][1], acc[i][2], acc[i][3]);
      *(float4*)(orow + cB) = make_float4(acc[i][4], acc[i][5], acc[i][6], acc[i][7]);
    }
    acc[i][0] = acc[i][1] = acc[i][2] = acc[i][3] = 0.f;
    acc[i][4] = acc[i][5] = acc[i][6] = acc[i][7] = 0.f;
  }

  GEMM_CHUNKS(Wp1 + (size_t)DD * DD)

  const float4 bA = *(const float4*)(bp1 + cA);
  const float4 bB = *(const float4*)(bp1 + cB);
#pragma unroll
  for (int i = 0; i < 4; ++i) {
    const int r = r0 + i;
    if (r >= nr) continue;
    float* orow = P2 + (size_t)(row0 + r) * DD;
    *(float4*)(orow + cA) = make_float4(acc[i][0] + bA.x, acc[i][1] + bA.y,
                                        acc[i][2] + bA.z, acc[i][3] + bA.w);
    *(float4*)(orow + cB) = make_float4(acc[i][4] + bB.x, acc[i][5] + bB.y,
                                        acc[i][6] + bB.z, acc[i][7] + bB.w);
  }
}

// ------------------------------------------------- final edge pass (node-parallel)
// For node d: P2row resident in regs; per incoming edge gather P1[src],
// out[eid] = sum_h relu(P1+P2)*Wp2 + bp2.  32-lane slot per node.
__global__ __launch_bounds__(256) void edge_out(
    const float4* __restrict__ P1_4, const float4* __restrict__ P2_4,
    const int* __restrict__ offs, const int* __restrict__ srcs_s,
    const int* __restrict__ eid_s, const float4* __restrict__ Wp2_4,
    const float* __restrict__ bp2, float* __restrict__ out) {
  const int slot = threadIdx.x >> 5, lane = threadIdx.x & 31;
  const int n = blockIdx.x * 8 + slot;
  if (n >= NN) return;
  const float4 p2 = P2_4[(size_t)n * 32 + lane];
  const float4 w = Wp2_4[lane];
  const float bb = bp2[0];
  const int beg = offs[n], end = offs[n + 1];
  int i = beg;
  for (; i + 2 <= end; i += 2) {
    const int s0 = srcs_s[i], s1 = srcs_s[i + 1];
    const int e0 = eid_s[i], e1 = eid_s[i + 1];
    const float4 q0 = P1_4[(size_t)s0 * 32 + lane];
    const float4 q1 = P1_4[(size_t)s1 * 32 + lane];
    float v0 = fmaxf(q0.x + p2.x, 0.f) * w.x + fmaxf(q0.y + p2.y, 0.f) * w.y
             + fmaxf(q0.z + p2.z, 0.f) * w.z + fmaxf(q0.w + p2.w, 0.f) * w.w;
    float v1 = fmaxf(q1.x + p2.x, 0.f) * w.x + fmaxf(q1.y + p2.y, 0.f) * w.y
             + fmaxf(q1.z + p2.z, 0.f) * w.z + fmaxf(q1.w + p2.w, 0.f) * w.w;
#pragma unroll
    for (int m = 16; m >= 1; m >>= 1) {
      v0 += __shfl_xor(v0, m, 64);
      v1 += __shfl_xor(v1, m, 64);
    }
    if (lane == 0) { out[e0] = v0 + bb; out[e1] = v1 + bb; }
  }
  if (i < end) {
    const int s0 = srcs_s[i];
    const int e0 = eid_s[i];
    const float4 q0 = P1_4[(size_t)s0 * 32 + lane];
    float v0 = fmaxf(q0.x + p2.x, 0.f) * w.x + fmaxf(q0.y + p2.y, 0.f) * w.y
             + fmaxf(q0.z + p2.z, 0.f) * w.z + fmaxf(q0.w + p2.w, 0.f) * w.w;
#pragma unroll
    for (int m = 16; m >= 1; m >>= 1) v0 += __shfl_xor(v0, m, 64);
    if (lane == 0) out[e0] = v0 + bb;
  }
}

// ---------------------------------------------------------------- launch
extern "C" void kernel_launch(void* const* d_in, const int* in_sizes, int n_in,
                              void* d_out, int out_size, void* d_ws, size_t ws_size,
                              hipStream_t stream) {
  const float* x_in = (const float*)d_in[0];
  const float* ea   = (const float*)d_in[1];
  const int*   ei   = (const int*)d_in[2];   // integer inputs arrive as int32
  const float* Wl1 = (const float*)d_in[3];
  const float* bl1 = (const float*)d_in[4];
  const float* Wl2 = (const float*)d_in[5];
  const float* bl2 = (const float*)d_in[6];
  const float* We  = (const float*)d_in[7];
  const float* be  = (const float*)d_in[8];
  const float* Wp1 = (const float*)d_in[9];
  const float* bp1 = (const float*)d_in[10];
  const float* Wp2 = (const float*)d_in[11];
  const float* bp2 = (const float*)d_in[12];
  const int* src = ei;
  const int* dst = ei + NE;

  // workspace layout (~61.5 MB)
  float* bufA   = (float*)d_ws;                    // NN*DD
  float* bufB   = bufA + (size_t)NN * DD;          // NN*DD
  int*   cnt    = (int*)(bufB + (size_t)NN * DD);  // NN
  int*   offs   = cnt + NN;                        // NN+1
  int*   cursor = offs + NN + 1;                   // NN
  int*   srcs_s = cursor + NN;                     // NE
  float* eas_s  = (float*)(srcs_s + NE);           // NE
  int*   eid_s  = (int*)(eas_s + NE);              // NE

  // CSR build (per-launch, deterministic work)
  hipMemsetAsync(cnt, 0, NN * sizeof(int), stream);
  hist_dst<<<NE / 256, 256, 0, stream>>>(dst, cnt);
  scan_nodes<<<1, 1024, 0, stream>>>(cnt, offs, cursor);
  csr_fill<<<NE / 256, 256, 0, stream>>>(src, dst, ea, cursor, srcs_s, eas_s, eid_s);

  const int mlpBlocks = (NN + 63) / 64;
  const int aggBlocks = (NN + 7) / 8;
  const float* xl = x_in;
  float* bufs[2] = {bufA, bufB};
  for (int l = 0; l < 3; ++l) {
    float* cur = bufs[l & 1];
    aggregate<<<aggBlocks, 256, 0, stream>>>(
        xl, offs, srcs_s, eas_s, (const float4*)(We + l * DD),
        (const float4*)(be + l * DD), cur);
    fused_mlp<<<mlpBlocks, 256, 0, stream>>>(
        cur, Wl1 + (size_t)l * DD * DD, bl1 + l * DD,
        Wl2 + (size_t)l * DD * DD, bl2 + l * DD, cur, NN);
    xl = cur;
  }
  // xl == bufA. P1 -> bufA (in place), P2 -> bufB.
  gemm_pred<<<mlpBlocks, 256, 0, stream>>>(bufA, Wp1, bp1, bufA, bufB, NN);
  edge_out<<<aggBlocks, 256, 0, stream>>>(
      (const float4*)bufA, (const float4*)bufB, offs, srcs_s, eid_s,
      (const float4*)Wp2, bp2, (float*)d_out);
}